// Round 1
// baseline (112.959 us; speedup 1.0000x reference)
//
#include <hip/hip_runtime.h>
#include <hip/hip_bf16.h>

#define DIM    256
#define NROWS  8192
#define NHALF  4096
#define NTILE  64          // 8192 / 128 tiles per dim

typedef unsigned short ushort_t;
using bf16x8 = __attribute__((ext_vector_type(8))) short;   // 8 bf16 in 4 VGPRs
using f32x4  = __attribute__((ext_vector_type(4))) float;   // MFMA C/D

__device__ __forceinline__ float bf_to_f(ushort_t u) {
  unsigned int x = ((unsigned int)u) << 16;
  return __builtin_bit_cast(float, x);
}
__device__ __forceinline__ ushort_t f_to_bf(float f) {
  unsigned int x = __builtin_bit_cast(unsigned int, f);
  unsigned int r = (x + 0x7fffu + ((x >> 16) & 1u)) >> 16;
  return (ushort_t)r;
}

// ---- kernel 0: zero the two double accumulators (ws is poisoned each call)
__global__ void zero_acc(double* acc) {
  acc[0] = 0.0;   // gram sum S = T_full + all_diag
  acc[1] = 0.0;   // sim_s
}

// ---- kernel 1: row-normalize x (fp32) -> z (bf16), one wave per row
__global__ __launch_bounds__(256) void normalize_k(const float* __restrict__ x,
                                                   ushort_t* __restrict__ z) {
  const int row  = blockIdx.x * 4 + (threadIdx.x >> 6);
  const int lane = threadIdx.x & 63;
  float4 v = ((const float4*)(x + (size_t)row * DIM))[lane];
  float ss = v.x * v.x + v.y * v.y + v.z * v.z + v.w * v.w;
#pragma unroll
  for (int off = 32; off > 0; off >>= 1) ss += __shfl_xor(ss, off, 64);
  float rn = rsqrtf(fmaxf(ss, 1e-24f));
  ushort4 o;
  o.x = f_to_bf(v.x * rn);
  o.y = f_to_bf(v.y * rn);
  o.z = f_to_bf(v.z * rn);
  o.w = f_to_bf(v.w * rn);
  ((ushort4*)(z + (size_t)row * DIM))[lane] = o;
}

// ---- kernel 2: Gram exp-sum over upper-triangular 128x128 tiles.
// Off-diagonal tiles weighted 2 (symmetry); diagonal entries i==j get an
// extra +1 so the accumulator equals T_full + all_diag.
__global__ __launch_bounds__(256, 2) void gram_k(const ushort_t* __restrict__ z,
                                                 double* __restrict__ acc) {
  __shared__ ushort_t As[128 * 64];
  __shared__ ushort_t Bs[128 * 64];
  __shared__ float wsum[4];

  // decode linear block id -> (bi, bj) with bi <= bj, start(b) = b*(129-b)/2
  const int bid = blockIdx.x;
  int bi = (int)((129.0 - sqrt(129.0 * 129.0 - 8.0 * (double)bid)) * 0.5);
  while ((bi * (129 - bi)) / 2 > bid) --bi;
  while (((bi + 1) * (128 - bi)) / 2 <= bid) ++bi;
  const int bj = bi + (bid - (bi * (129 - bi)) / 2);

  const int tid  = threadIdx.x;
  const int lane = tid & 63;
  const int w    = tid >> 6;
  const int wr   = w >> 1, wc = w & 1;        // 2x2 wave grid, 64x64 each
  const int r16  = lane & 15, quad = lane >> 4;

  const size_t rowA0 = (size_t)bi * 128;
  const size_t rowB0 = (size_t)bj * 128;

  f32x4 acc_f[4][4] = {};

  for (int kb = 0; kb < 4; ++kb) {
    // stage 128x64 A and B tiles via global_load_lds (16B/lane).
    // LDS slot (row, cb) holds global colblock cb ^ (row&7)  (XOR swizzle
    // applied on the GLOBAL side since glds forces dest = base + lane*16).
#pragma unroll
    for (int i = 0; i < 4; ++i) {
      int chunk = i * 256 + tid;            // 0..1023 -> (row, colblock)
      int row   = chunk >> 3;               // 0..127
      int cb    = chunk & 7;
      int gcb   = cb ^ (row & 7);
      const ushort_t* ga = z + (rowA0 + row) * DIM + kb * 64 + gcb * 8;
      const ushort_t* gb = z + (rowB0 + row) * DIM + kb * 64 + gcb * 8;
      __builtin_amdgcn_global_load_lds(
          (__attribute__((address_space(1))) void*)ga,
          (__attribute__((address_space(3))) void*)&As[(size_t)(i * 256 + (tid & ~63)) * 8],
          16, 0, 0);
      __builtin_amdgcn_global_load_lds(
          (__attribute__((address_space(1))) void*)gb,
          (__attribute__((address_space(3))) void*)&Bs[(size_t)(i * 256 + (tid & ~63)) * 8],
          16, 0, 0);
    }
    __syncthreads();

#pragma unroll
    for (int s = 0; s < 2; ++s) {
      bf16x8 af[4], bfr[4];
#pragma unroll
      for (int t = 0; t < 4; ++t) {
        int ar  = wr * 64 + t * 16 + r16;
        int acb = (s * 4 + quad) ^ (ar & 7);
        af[t]  = *(const bf16x8*)&As[ar * 64 + acb * 8];
        int br  = wc * 64 + t * 16 + r16;
        int bcb = (s * 4 + quad) ^ (br & 7);
        bfr[t] = *(const bf16x8*)&Bs[br * 64 + bcb * 8];
      }
#pragma unroll
      for (int ti = 0; ti < 4; ++ti)
#pragma unroll
        for (int tj = 0; tj < 4; ++tj)
          acc_f[ti][tj] = __builtin_amdgcn_mfma_f32_16x16x32_bf16(
              af[ti], bfr[tj], acc_f[ti][tj], 0, 0, 0);
    }
    __syncthreads();
  }

  // epilogue: coef * exp(cos/TEMP), TEMP = 2
  const float base_coef = (bi < bj) ? 2.0f : 1.0f;
  float lsum = 0.0f;
#pragma unroll
  for (int ti = 0; ti < 4; ++ti) {
#pragma unroll
    for (int tj = 0; tj < 4; ++tj) {
#pragma unroll
      for (int v = 0; v < 4; ++v) {
        float d = acc_f[ti][tj][v];
        float e = __expf(d * 0.5f);
        float c = base_coef;
        if (bi == bj) {
          int gi = wr * 64 + ti * 16 + quad * 4 + v;   // C/D row
          int gj = wc * 64 + tj * 16 + r16;            // C/D col
          if (gi == gj) c = 2.0f;                      // T_full + all_diag
        }
        lsum += c * e;
      }
    }
  }
#pragma unroll
  for (int off = 32; off > 0; off >>= 1) lsum += __shfl_xor(lsum, off, 64);
  if (lane == 0) wsum[w] = lsum;
  __syncthreads();
  if (tid == 0) {
    float bsum = wsum[0] + wsum[1] + wsum[2] + wsum[3];
    atomicAdd(acc, (double)bsum);
  }
}

// ---- kernel 3: sim_s = sum_i exp(z_i . z_{i+4096} / 2), one wave per i
__global__ __launch_bounds__(256) void diag_k(const ushort_t* __restrict__ z,
                                              double* __restrict__ acc) {
  __shared__ float wsum[4];
  const int i    = blockIdx.x * 4 + (threadIdx.x >> 6);
  const int lane = threadIdx.x & 63;
  ushort4 a = ((const ushort4*)(z + (size_t)i * DIM))[lane];
  ushort4 b = ((const ushort4*)(z + (size_t)(i + NHALF) * DIM))[lane];
  float s = bf_to_f(a.x) * bf_to_f(b.x) + bf_to_f(a.y) * bf_to_f(b.y) +
            bf_to_f(a.z) * bf_to_f(b.z) + bf_to_f(a.w) * bf_to_f(b.w);
#pragma unroll
  for (int off = 32; off > 0; off >>= 1) s += __shfl_xor(s, off, 64);
  if (lane == 0) wsum[threadIdx.x >> 6] = __expf(s * 0.5f);
  __syncthreads();
  if (threadIdx.x == 0)
    atomicAdd(acc + 1, (double)(wsum[0] + wsum[1] + wsum[2] + wsum[3]));
}

// ---- kernel 4: out = log(sim_all) - log(sim_s), sim_all = S/2 + sim_s
__global__ void finalize_k(const double* __restrict__ acc, float* __restrict__ out) {
  double S  = acc[0];
  double ss = acc[1];
  double sim_all = 0.5 * S + ss;
  out[0] = (float)(log(sim_all) - log(ss));
}

extern "C" void kernel_launch(void* const* d_in, const int* in_sizes, int n_in,
                              void* d_out, int out_size, void* d_ws, size_t ws_size,
                              hipStream_t stream) {
  const float* x = (const float*)d_in[0];
  ushort_t* z    = (ushort_t*)d_ws;                               // 8192*256 bf16 = 4 MB
  double* acc    = (double*)((char*)d_ws + (size_t)NROWS * DIM * sizeof(ushort_t));
  float* out     = (float*)d_out;

  zero_acc<<<dim3(1), dim3(1), 0, stream>>>(acc);
  normalize_k<<<dim3(NROWS / 4), dim3(256), 0, stream>>>(x, z);
  gram_k<<<dim3((NTILE * (NTILE + 1)) / 2), dim3(256), 0, stream>>>(z, acc);  // 2080 tiles
  diag_k<<<dim3(NHALF / 4), dim3(256), 0, stream>>>(z, acc);
  finalize_k<<<dim3(1), dim3(1), 0, stream>>>(acc, out);
}

// Round 2
// 94.817 us; speedup vs baseline: 1.1913x; 1.1913x over previous
//
#include <hip/hip_runtime.h>

#define DIM    256
#define NROWS  8192
#define NHALF  4096
#define NTILE  64          // 8192 / 128 tiles per dim

using i32x4  = __attribute__((ext_vector_type(4))) int;
using i32x8  = __attribute__((ext_vector_type(8))) int;
using f32x16 = __attribute__((ext_vector_type(16))) float;

struct i32x8_pair { i32x4 lo, hi; };

// ---- kernel 1: row-normalize x (fp32) -> z8 (fp8 e4m3), one wave per row.
// Block 0 also zeroes the two double accumulators (ws is poisoned each call).
__global__ __launch_bounds__(256) void normalize_k(const float* __restrict__ x,
                                                   unsigned char* __restrict__ z8,
                                                   double* __restrict__ acc) {
  if (blockIdx.x == 0 && threadIdx.x < 2) acc[threadIdx.x] = 0.0;
  const int row  = blockIdx.x * 4 + (threadIdx.x >> 6);
  const int lane = threadIdx.x & 63;
  float4 v = ((const float4*)(x + (size_t)row * DIM))[lane];
  float ss = v.x * v.x + v.y * v.y + v.z * v.z + v.w * v.w;
#pragma unroll
  for (int off = 32; off > 0; off >>= 1) ss += __shfl_xor(ss, off, 64);
  float rn = rsqrtf(fmaxf(ss, 1e-24f));
  // HW OCP-e4m3 pack: bytes [v.x, v.y, v.z, v.w] in increasing k order
  int p = __builtin_amdgcn_cvt_pk_fp8_f32(v.x * rn, v.y * rn, 0, false);
  p     = __builtin_amdgcn_cvt_pk_fp8_f32(v.z * rn, v.w * rn, p, true);
  ((int*)(z8 + (size_t)row * DIM))[lane] = p;
}

// ---- kernel 2: Gram exp-sum over upper-triangular 128x128 tiles, MX-fp8.
// acc[0] += coef * exp(cos/2)  (coef 2 off-diag-tile, diag entries get +1)
// acc[1] += exp(cos/2) over the (i, i+4096) diagonal (tiles bj == bi+32).
__global__ __launch_bounds__(256, 3) void gram_k(const unsigned char* __restrict__ z8,
                                                 double* __restrict__ acc) {
  __shared__ unsigned char As[128 * 128];
  __shared__ unsigned char Bs[128 * 128];
  __shared__ float red[8];

  // linear block id -> (bi, bj), bi <= bj
  const int bid = blockIdx.x;
  int bi = (int)((129.0 - sqrt(129.0 * 129.0 - 8.0 * (double)bid)) * 0.5);
  while ((bi * (129 - bi)) / 2 > bid) --bi;
  while (((bi + 1) * (128 - bi)) / 2 <= bid) ++bi;
  const int bj = bi + (bid - (bi * (129 - bi)) / 2);

  const int tid   = threadIdx.x;
  const int lane  = tid & 63;
  const int w     = tid >> 6;
  const int wr    = w >> 1, wc = w & 1;     // 2x2 wave grid, 64x64 each
  const int l31   = lane & 31;
  const int khalf = lane >> 5;              // K-half selector for 32x32 frags

  const size_t rowA0 = (size_t)bi * 128;
  const size_t rowB0 = (size_t)bj * 128;

  f32x16 acc_f[2][2] = {};

  for (int kb = 0; kb < 2; ++kb) {          // two BK=128 staging rounds
    // stage 128 rows x 128 fp8 bytes for A and B via global_load_lds, 16B/lane.
    // LDS colblock cb holds global colblock cb ^ (row&7) (swizzle applied on
    // the global side: glds forces dest = wave-uniform base + lane*16).
#pragma unroll
    for (int i = 0; i < 4; ++i) {
      int c   = i * 256 + tid;              // 0..1023 -> (row, colblock)
      int row = c >> 3;                     // 0..127
      int cb  = c & 7;
      int gcb = cb ^ (row & 7);
      const unsigned char* ga = z8 + (rowA0 + row) * DIM + kb * 128 + gcb * 16;
      const unsigned char* gb = z8 + (rowB0 + row) * DIM + kb * 128 + gcb * 16;
      __builtin_amdgcn_global_load_lds(
          (const __attribute__((address_space(1))) void*)ga,
          (__attribute__((address_space(3))) void*)&As[(size_t)(i * 256 + (tid & ~63)) * 16],
          16, 0, 0);
      __builtin_amdgcn_global_load_lds(
          (const __attribute__((address_space(1))) void*)gb,
          (__attribute__((address_space(3))) void*)&Bs[(size_t)(i * 256 + (tid & ~63)) * 16],
          16, 0, 0);
    }
    __syncthreads();

#pragma unroll
    for (int kc = 0; kc < 2; ++kc) {        // two K=64 MFMA chunks per round
      i32x8 a[2], b[2];
#pragma unroll
      for (int t = 0; t < 2; ++t) {
        const int cb0 = kc * 4 + khalf * 2; // first 16B colblock of lane's 32B
        int mr = wr * 64 + t * 32 + l31;
        i32x8_pair pa = { *(const i32x4*)&As[mr * 128 + ((cb0    ) ^ (mr & 7)) * 16],
                          *(const i32x4*)&As[mr * 128 + ((cb0 + 1) ^ (mr & 7)) * 16] };
        a[t] = __builtin_bit_cast(i32x8, pa);
        int nr = wc * 64 + t * 32 + l31;
        i32x8_pair pb = { *(const i32x4*)&Bs[nr * 128 + ((cb0    ) ^ (nr & 7)) * 16],
                          *(const i32x4*)&Bs[nr * 128 + ((cb0 + 1) ^ (nr & 7)) * 16] };
        b[t] = __builtin_bit_cast(i32x8, pb);
      }
#pragma unroll
      for (int ti = 0; ti < 2; ++ti)
#pragma unroll
        for (int tj = 0; tj < 2; ++tj)
          acc_f[ti][tj] = __builtin_amdgcn_mfma_scale_f32_32x32x64_f8f6f4(
              a[ti], b[tj], acc_f[ti][tj],
              0, 0,                         // cbsz/blgp: fp8 e4m3 A and B
              0, 0x7f7f7f7f,                // scale_a = 1.0 (E8M0 127)
              0, 0x7f7f7f7f);               // scale_b = 1.0
    }
    __syncthreads();
  }

  // epilogue: coef * exp(cos/TEMP), TEMP = 2; fused sim_s diagonal
  const float base_coef = (bi < bj) ? 2.0f : 1.0f;
  const bool  sdiag     = (bj == bi + 32);
  float lsum = 0.0f, ssum = 0.0f;
#pragma unroll
  for (int ti = 0; ti < 2; ++ti) {
#pragma unroll
    for (int tj = 0; tj < 2; ++tj) {
#pragma unroll
      for (int r = 0; r < 16; ++r) {
        float e = __expf(acc_f[ti][tj][r] * 0.5f);
        // 32x32 C/D layout: col = lane&31, row = (reg&3) + 8*(reg>>2) + 4*khalf
        int row_l = (r & 3) + 8 * (r >> 2) + 4 * khalf;
        int gi = wr * 64 + ti * 32 + row_l;
        int gj = wc * 64 + tj * 32 + l31;
        float c = base_coef;
        if (bi == bj && gi == gj) c = 2.0f;  // accumulate T_full + all_diag
        lsum += c * e;
        if (sdiag && gi == gj) ssum += e;    // sim_s terms
      }
    }
  }
#pragma unroll
  for (int off = 32; off > 0; off >>= 1) lsum += __shfl_xor(lsum, off, 64);
  if (sdiag) {
#pragma unroll
    for (int off = 32; off > 0; off >>= 1) ssum += __shfl_xor(ssum, off, 64);
  }
  if (lane == 0) { red[w] = lsum; red[4 + w] = ssum; }
  __syncthreads();
  if (tid == 0)
    atomicAdd(acc, (double)(red[0] + red[1] + red[2] + red[3]));
  if (tid == 64 && sdiag)
    atomicAdd(acc + 1, (double)(red[4] + red[5] + red[6] + red[7]));
}

// ---- kernel 3: out = log(sim_all) - log(sim_s), sim_all = S/2 + sim_s
__global__ void finalize_k(const double* __restrict__ acc, float* __restrict__ out) {
  double S  = acc[0];
  double ss = acc[1];
  double sim_all = 0.5 * S + ss;
  out[0] = (float)(log(sim_all) - log(ss));
}

extern "C" void kernel_launch(void* const* d_in, const int* in_sizes, int n_in,
                              void* d_out, int out_size, void* d_ws, size_t ws_size,
                              hipStream_t stream) {
  const float* x    = (const float*)d_in[0];
  unsigned char* z8 = (unsigned char*)d_ws;                        // 8192*256 fp8 = 2 MB
  double* acc       = (double*)((char*)d_ws + (size_t)NROWS * DIM);
  float* out        = (float*)d_out;

  normalize_k<<<dim3(NROWS / 4), dim3(256), 0, stream>>>(x, z8, acc);
  gram_k<<<dim3((NTILE * (NTILE + 1)) / 2), dim3(256), 0, stream>>>(z8, acc);  // 2080 tiles
  finalize_k<<<dim3(1), dim3(1), 0, stream>>>(acc, out);
}